// Round 1
// baseline (7051.406 us; speedup 1.0000x reference)
//
#include <hip/hip_runtime.h>
#include <math.h>

#define H 128
#define NFACT 100000
#define NCOMP 2000
#define NEDGE 800000
#define BGRAPH 256
#define DF 1536
#define DC 27
#define LEPS 1e-5f
#define MC_REP 8

__device__ __forceinline__ float sigmoidf(float x) { return 1.0f / (1.0f + __expf(-x)); }

__device__ __forceinline__ int lowerb(const int* __restrict__ a, int n, int v) {
    int lo = 0, hi = n;
    while (lo < hi) { int mid = (lo + hi) >> 1; if (a[mid] < v) lo = mid + 1; else hi = mid; }
    return lo;
}

// ---------------- runtime detection of primary_mask storage (u8 bool vs i32) --------
// int32 layout of 0/1 values => bytes at i%4!=0 are all zero. u8 layout => ~half nonzero.
__global__ void mask_detect(const unsigned char* __restrict__ m, int n, int* __restrict__ flag) {
    __shared__ int f;
    if (threadIdx.x == 0) f = 0;
    __syncthreads();
    int local = 0;
    for (int i = threadIdx.x; i < n; i += blockDim.x)
        if ((i & 3) && m[i]) local = 1;
    if (local) atomicOr(&f, 1);
    __syncthreads();
    if (threadIdx.x == 0) *flag = f;
}

// ---------------- fact encoder GEMM: out[m][h] = sum_k X[m][k]*W[h][k] + bias[h] -----
__global__ __launch_bounds__(256)
void gemm_bias_xwT(const float* __restrict__ X, const float* __restrict__ W,
                   const float* __restrict__ bias, float* __restrict__ out,
                   int M, int K) {
    __shared__ __align__(16) float As[16][68];    // [k][row]
    __shared__ __align__(16) float Bs[16][132];   // [k][col(h)]
    const int tid = threadIdx.x;
    const int m0 = blockIdx.x * 64;
    const int tx = tid & 31;        // col group: cols tx*4..tx*4+3
    const int ty = tid >> 5;        // row group: rows ty*8..ty*8+7
    float acc[8][4];
#pragma unroll
    for (int i = 0; i < 8; ++i)
#pragma unroll
        for (int j = 0; j < 4; ++j) acc[i][j] = 0.f;

    const int lr = tid >> 2;        // A loader: row 0..63
    const int lkq = tid & 3;        // A loader: k quad
    int arow = m0 + lr; if (arow > M - 1) arow = M - 1;
    const float* xrow = X + (size_t)arow * K;
    const int ln = tid >> 1;        // B loader: h 0..127
    const int lh = tid & 1;         // B loader: k half
    const float* wrow = W + (size_t)ln * K;

    for (int k0 = 0; k0 < K; k0 += 16) {
        float4 av  = *(const float4*)(xrow + k0 + lkq * 4);
        float4 bv0 = *(const float4*)(wrow + k0 + lh * 8);
        float4 bv1 = *(const float4*)(wrow + k0 + lh * 8 + 4);
        __syncthreads();
        As[lkq * 4 + 0][lr] = av.x; As[lkq * 4 + 1][lr] = av.y;
        As[lkq * 4 + 2][lr] = av.z; As[lkq * 4 + 3][lr] = av.w;
        {
            int kb = lh * 8;
            Bs[kb + 0][ln] = bv0.x; Bs[kb + 1][ln] = bv0.y;
            Bs[kb + 2][ln] = bv0.z; Bs[kb + 3][ln] = bv0.w;
            Bs[kb + 4][ln] = bv1.x; Bs[kb + 5][ln] = bv1.y;
            Bs[kb + 6][ln] = bv1.z; Bs[kb + 7][ln] = bv1.w;
        }
        __syncthreads();
#pragma unroll
        for (int k = 0; k < 16; ++k) {
            float4 a0 = *(const float4*)&As[k][ty * 8];
            float4 a1 = *(const float4*)&As[k][ty * 8 + 4];
            float4 b  = *(const float4*)&Bs[k][tx * 4];
            float a[8] = {a0.x, a0.y, a0.z, a0.w, a1.x, a1.y, a1.z, a1.w};
            float bb[4] = {b.x, b.y, b.z, b.w};
#pragma unroll
            for (int i = 0; i < 8; ++i)
#pragma unroll
                for (int j = 0; j < 4; ++j) acc[i][j] += a[i] * bb[j];
        }
    }
    float4 bsv = *(const float4*)(bias + tx * 4);
#pragma unroll
    for (int i = 0; i < 8; ++i) {
        int r = m0 + ty * 8 + i;
        if (r < M) {
            float4 o;
            o.x = acc[i][0] + bsv.x; o.y = acc[i][1] + bsv.y;
            o.z = acc[i][2] + bsv.z; o.w = acc[i][3] + bsv.w;
            *(float4*)(out + (size_t)r * H + tx * 4) = o;
        }
    }
}

// ---------------- fact combine: msg = msg@Wrel^T + brel + root@Wroot^T (in-place) ----
__global__ __launch_bounds__(256)
void gemm_combine_f(float* __restrict__ msg, const float* __restrict__ root,
                    const float* __restrict__ Wrel, const float* __restrict__ Wroot,
                    const float* __restrict__ brel, int M) {
    __shared__ __align__(16) float As[16][68];
    __shared__ __align__(16) float Bs[16][132];
    const int tid = threadIdx.x;
    const int m0 = blockIdx.x * 64;
    const int tx = tid & 31;
    const int ty = tid >> 5;
    float acc[8][4];
#pragma unroll
    for (int i = 0; i < 8; ++i)
#pragma unroll
        for (int j = 0; j < 4; ++j) acc[i][j] = 0.f;

    const int lr = tid >> 2;
    const int lkq = tid & 3;
    int arow = m0 + lr; if (arow > M - 1) arow = M - 1;
    const int ln = tid >> 1;
    const int lh = tid & 1;

    for (int k0 = 0; k0 < 256; k0 += 16) {
        int ka = k0 + lkq * 4;
        const float* asrc = (ka < 128) ? (msg + (size_t)arow * H + ka)
                                       : (root + (size_t)arow * H + (ka - 128));
        float4 av = *(const float4*)asrc;
        int kb = k0 + lh * 8;
        const float* bsrc = (kb < 128) ? (Wrel + (size_t)ln * H + kb)
                                       : (Wroot + (size_t)ln * H + (kb - 128));
        float4 bv0 = *(const float4*)bsrc;
        float4 bv1 = *(const float4*)(bsrc + 4);
        __syncthreads();
        As[lkq * 4 + 0][lr] = av.x; As[lkq * 4 + 1][lr] = av.y;
        As[lkq * 4 + 2][lr] = av.z; As[lkq * 4 + 3][lr] = av.w;
        {
            int kk = lh * 8;
            Bs[kk + 0][ln] = bv0.x; Bs[kk + 1][ln] = bv0.y;
            Bs[kk + 2][ln] = bv0.z; Bs[kk + 3][ln] = bv0.w;
            Bs[kk + 4][ln] = bv1.x; Bs[kk + 5][ln] = bv1.y;
            Bs[kk + 6][ln] = bv1.z; Bs[kk + 7][ln] = bv1.w;
        }
        __syncthreads();
#pragma unroll
        for (int k = 0; k < 16; ++k) {
            float4 a0 = *(const float4*)&As[k][ty * 8];
            float4 a1 = *(const float4*)&As[k][ty * 8 + 4];
            float4 b  = *(const float4*)&Bs[k][tx * 4];
            float a[8] = {a0.x, a0.y, a0.z, a0.w, a1.x, a1.y, a1.z, a1.w};
            float bb[4] = {b.x, b.y, b.z, b.w};
#pragma unroll
            for (int i = 0; i < 8; ++i)
#pragma unroll
                for (int j = 0; j < 4; ++j) acc[i][j] += a[i] * bb[j];
        }
    }
    float4 bsv = *(const float4*)(brel + tx * 4);
#pragma unroll
    for (int i = 0; i < 8; ++i) {
        int r = m0 + ty * 8 + i;
        if (r < M) {
            float4 o;
            o.x = acc[i][0] + bsv.x; o.y = acc[i][1] + bsv.y;
            o.z = acc[i][2] + bsv.z; o.w = acc[i][3] + bsv.w;
            *(float4*)(msg + (size_t)r * H + tx * 4) = o;
        }
    }
}

// ---------------- company encoder (tiny K=27) ----------------------------------------
__global__ __launch_bounds__(128)
void enc_comp(const float* __restrict__ X, const float* __restrict__ W,
              const float* __restrict__ bias, float* __restrict__ out) {
    __shared__ float xr[DC];
    int n = blockIdx.x, h = threadIdx.x;
    if (h < DC) xr[h] = X[(size_t)n * DC + h];
    __syncthreads();
    float acc = bias[h];
    const float* w = W + (size_t)h * DC;
#pragma unroll
    for (int d = 0; d < DC; ++d) acc += xr[d] * w[d];
    out[(size_t)n * H + h] = acc;
}

// ---------------- company combine (+8-way replica reduce of msg_c) -------------------
__global__ __launch_bounds__(128)
void combine_c(const float* __restrict__ mcrep, const float* __restrict__ hc,
               const float* __restrict__ Wrel, const float* __restrict__ Wroot,
               const float* __restrict__ brel, float* __restrict__ out) {
    __shared__ float rowA[H];
    __shared__ float rowB[H];
    int n = blockIdx.x, h = threadIdx.x;
    float m = 0.f;
#pragma unroll
    for (int r = 0; r < MC_REP; ++r)
        m += mcrep[(size_t)r * NCOMP * H + (size_t)n * H + h];
    rowA[h] = m;
    rowB[h] = hc[(size_t)n * H + h];
    __syncthreads();
    float acc = brel[h];
    const float* wr = Wrel + (size_t)h * H;
    const float* wo = Wroot + (size_t)h * H;
#pragma unroll 4
    for (int k = 0; k < H; ++k) acc += rowA[k] * wr[k] + rowB[k] * wo[k];
    out[(size_t)n * H + h] = acc;
}

// ---------------- relu + LayerNorm over H, in place (wave per row) -------------------
__global__ __launch_bounds__(256)
void relu_ln_rows(float* __restrict__ data, int M,
                  const float* __restrict__ g, const float* __restrict__ b) {
    int row = blockIdx.x * 4 + (threadIdx.x >> 6);
    int lane = threadIdx.x & 63;
    if (row >= M) return;
    float* p = data + (size_t)row * H;
    float2 v = *(float2*)(p + lane * 2);
    float x0 = fmaxf(v.x, 0.f), x1 = fmaxf(v.y, 0.f);
    float s = x0 + x1, q = x0 * x0 + x1 * x1;
#pragma unroll
    for (int o = 32; o > 0; o >>= 1) { s += __shfl_xor(s, o); q += __shfl_xor(q, o); }
    float mu = s * (1.f / H);
    float var = q * (1.f / H) - mu * mu;
    float rs = rsqrtf(var + LEPS);
    float2 gg = *(const float2*)(g + lane * 2);
    float2 bb = *(const float2*)(b + lane * 2);
    float2 o2;
    o2.x = (x0 - mu) * rs * gg.x + bb.x;
    o2.y = (x1 - mu) * rs * gg.y + bb.y;
    *(float2*)(p + lane * 2) = o2;
}

// ---------------- edge scatter: out[dst] += sigmoid(ea*wm+bm) * feat[src] ------------
__global__ __launch_bounds__(256)
void msg_scatter(const int* __restrict__ src, const int* __restrict__ dst,
                 const float* __restrict__ ea,
                 const float* __restrict__ wmix, const float* __restrict__ bmix,
                 const float* __restrict__ feat, float* __restrict__ out,
                 int rep_stride, int rep_mask) {
    int gid = blockIdx.x * 256 + threadIdx.x;
    int e = gid >> 5;
    if (e >= NEDGE) return;
    int h4 = gid & 31;
    float w = sigmoidf(ea[e] * wmix[0] + bmix[0]);
    int s = src[e], d = dst[e];
    const float4 v = *(const float4*)(feat + (size_t)s * H + h4 * 4);
    float* o = out + (size_t)(blockIdx.x & rep_mask) * rep_stride + (size_t)d * H + h4 * 4;
    atomicAdd(o + 0, w * v.x);
    atomicAdd(o + 1, w * v.y);
    atomicAdd(o + 2, w * v.z);
    atomicAdd(o + 3, w * v.w);
}

// ---------------- pooling ------------------------------------------------------------
__global__ __launch_bounds__(128)
void pool_fact(const float* __restrict__ hf, const int* __restrict__ batch,
               float* __restrict__ pool) {
    int b = blockIdx.x, h = threadIdx.x;
    int lo = lowerb(batch, NFACT, b), hi = lowerb(batch, NFACT, b + 1);
    float acc = 0.f;
    for (int r = lo; r < hi; ++r) acc += hf[(size_t)r * H + h];
    float cnt = (float)(hi - lo); if (cnt < 1.f) cnt = 1.f;
    pool[(size_t)b * H + h] = acc / cnt;
}

// NOTE: reference applies maximum(cnt_m,1) BEFORE the where(cnt_m>1e-6,...) test, so
// the fallback branch is dead: comp_pool is ALWAYS sum_masked / max(cnt_masked, 1).
__global__ __launch_bounds__(128)
void pool_comp(const float* __restrict__ hc, const int* __restrict__ batch,
               const void* __restrict__ maskp, const int* __restrict__ flag,
               float* __restrict__ pool) {
    int b = blockIdx.x, h = threadIdx.x;
    int lo = lowerb(batch, NCOMP, b), hi = lowerb(batch, NCOMP, b + 1);
    int isU8 = *flag;
    const unsigned char* m8 = (const unsigned char*)maskp;
    const int* m32 = (const int*)maskp;
    float acc = 0.f, cnt = 0.f;
    for (int r = lo; r < hi; ++r) {
        float m = isU8 ? (m8[r] ? 1.f : 0.f) : (m32[r] ? 1.f : 0.f);
        acc += m * hc[(size_t)r * H + h];
        cnt += m;
    }
    if (cnt < 1.f) cnt = 1.f;
    pool[(size_t)b * H + h] = acc / cnt;
}

// ---------------- gated readout + classifier -----------------------------------------
__global__ __launch_bounds__(128)
void gate_cls(const float* __restrict__ fp, const float* __restrict__ cp,
              const float* __restrict__ Wg, const float* __restrict__ bg,
              const float* __restrict__ Wc, const float* __restrict__ bc,
              float* __restrict__ out) {
    __shared__ float red[2];
    __shared__ float red2[2];
    int b = blockIdx.x, t = threadIdx.x;
    float f = fp[(size_t)b * H + t], c = cp[(size_t)b * H + t];
    float s = Wg[t] * f + Wg[H + t] * c;
#pragma unroll
    for (int o = 32; o > 0; o >>= 1) s += __shfl_xor(s, o);
    if ((t & 63) == 0) red[t >> 6] = s;
    __syncthreads();
    float S = red[0] + red[1];
    float alpha = sigmoidf(S + bg[0]);
    float v = (alpha * f + (1.f - alpha) * c) * Wc[t];
#pragma unroll
    for (int o = 32; o > 0; o >>= 1) v += __shfl_xor(v, o);
    if ((t & 63) == 0) red2[t >> 6] = v;
    __syncthreads();
    if (t == 0) out[b] = red2[0] + red2[1] + bc[0];
}

extern "C" void kernel_launch(void* const* d_in, const int* in_sizes, int n_in,
                              void* d_out, int out_size, void* d_ws, size_t ws_size,
                              hipStream_t stream) {
    const float* x_fact   = (const float*)d_in[0];
    const float* x_comp   = (const float*)d_in[1];
    const float* ea_fc    = (const float*)d_in[2];
    const float* ea_cf    = (const float*)d_in[3];
    const int*   src_fc   = (const int*)d_in[4];
    const int*   dst_fc   = (const int*)d_in[5];
    const int*   src_cf   = (const int*)d_in[6];
    const int*   dst_cf   = (const int*)d_in[7];
    const int*   fact_batch = (const int*)d_in[8];
    const int*   comp_batch = (const int*)d_in[9];
    const void*  pmask    = d_in[10];
    const float* W_in_f   = (const float*)d_in[11];
    const float* b_in_f   = (const float*)d_in[12];
    const float* g_in_f   = (const float*)d_in[13];
    const float* be_in_f  = (const float*)d_in[14];
    const float* W_in_c   = (const float*)d_in[15];
    const float* b_in_c   = (const float*)d_in[16];
    const float* g_in_c   = (const float*)d_in[17];
    const float* be_in_c  = (const float*)d_in[18];
    const float* w_mix    = (const float*)d_in[19];
    const float* b_mix    = (const float*)d_in[20];
    const float* Wrel_fc  = (const float*)d_in[21];
    const float* brel_fc  = (const float*)d_in[22];
    const float* Wroot_fc = (const float*)d_in[23];
    const float* Wrel_cf  = (const float*)d_in[24];
    const float* brel_cf  = (const float*)d_in[25];
    const float* Wroot_cf = (const float*)d_in[26];
    const float* g_post_f = (const float*)d_in[27];
    const float* b_post_f = (const float*)d_in[28];
    const float* g_post_c = (const float*)d_in[29];
    const float* b_post_c = (const float*)d_in[30];
    const float* W_gate   = (const float*)d_in[31];
    const float* b_gate   = (const float*)d_in[32];
    const float* W_cls    = (const float*)d_in[33];
    const float* b_cls    = (const float*)d_in[34];
    float* outp = (float*)d_out;
    (void)in_sizes; (void)n_in; (void)out_size; (void)ws_size;

    float* buf0  = (float*)d_ws;                        // hf ping  [NFACT,H]
    float* buf1  = buf0 + (size_t)NFACT * H;            // hf pong  [NFACT,H]
    float* hc0   = buf1 + (size_t)NFACT * H;            // hc ping  [NCOMP,H]
    float* hc1   = hc0 + (size_t)NCOMP * H;             // hc pong
    float* mcrep = hc1 + (size_t)NCOMP * H;             // msg_c replicas [8,NCOMP,H]
    float* fpool = mcrep + (size_t)MC_REP * NCOMP * H;  // [B,H]
    float* cpool = fpool + (size_t)BGRAPH * H;          // [B,H]
    int*   flag  = (int*)(cpool + (size_t)BGRAPH * H);

    mask_detect<<<1, 256, 0, stream>>>((const unsigned char*)pmask, NCOMP, flag);

    // encoders
    gemm_bias_xwT<<<(NFACT + 63) / 64, 256, 0, stream>>>(x_fact, W_in_f, b_in_f, buf0, NFACT, DF);
    relu_ln_rows<<<(NFACT + 3) / 4, 256, 0, stream>>>(buf0, NFACT, g_in_f, be_in_f);
    enc_comp<<<NCOMP, 128, 0, stream>>>(x_comp, W_in_c, b_in_c, hc0);
    relu_ln_rows<<<(NCOMP + 3) / 4, 256, 0, stream>>>(hc0, NCOMP, g_in_c, be_in_c);

    float* hf = buf0; float* hfN = buf1;
    float* hc = hc0;  float* hcN = hc1;
    const int msgBlocks = (NEDGE * 32) / 256;   // 100000

    for (int l = 0; l < 2; ++l) {
        hipMemsetAsync(mcrep, 0, (size_t)MC_REP * NCOMP * H * sizeof(float), stream);
        hipMemsetAsync(hfN, 0, (size_t)NFACT * H * sizeof(float), stream);
        // fact -> company messages (8-way replicated accumulator)
        msg_scatter<<<msgBlocks, 256, 0, stream>>>(src_fc, dst_fc, ea_fc, w_mix, b_mix,
                                                   hf, mcrep, NCOMP * H, MC_REP - 1);
        // company -> fact messages (low contention, direct)
        msg_scatter<<<msgBlocks, 256, 0, stream>>>(src_cf, dst_cf, ea_cf, w_mix, b_mix,
                                                   hc, hfN, 0, 0);
        gemm_combine_f<<<(NFACT + 63) / 64, 256, 0, stream>>>(hfN, hf,
            Wrel_cf + (size_t)l * H * H, Wroot_cf + (size_t)l * H * H, brel_cf + (size_t)l * H, NFACT);
        relu_ln_rows<<<(NFACT + 3) / 4, 256, 0, stream>>>(hfN, NFACT, g_post_f, b_post_f);
        combine_c<<<NCOMP, 128, 0, stream>>>(mcrep, hc,
            Wrel_fc + (size_t)l * H * H, Wroot_fc + (size_t)l * H * H, brel_fc + (size_t)l * H, hcN);
        relu_ln_rows<<<(NCOMP + 3) / 4, 256, 0, stream>>>(hcN, NCOMP, g_post_c, b_post_c);
        float* t = hf; hf = hfN; hfN = t;
        t = hc; hc = hcN; hcN = t;
    }

    pool_fact<<<BGRAPH, 128, 0, stream>>>(hf, fact_batch, fpool);
    pool_comp<<<BGRAPH, 128, 0, stream>>>(hc, comp_batch, pmask, flag, cpool);
    gate_cls<<<BGRAPH, 128, 0, stream>>>(fpool, cpool, W_gate, b_gate, W_cls, b_cls, outp);
}

// Round 2
// 2551.731 us; speedup vs baseline: 2.7634x; 2.7634x over previous
//
#include <hip/hip_runtime.h>
#include <math.h>

#define H 128
#define NFACT 100000
#define NCOMP 2000
#define NEDGE 800000
#define BGRAPH 256
#define DF 1536
#define DC 27
#define LEPS 1e-5f

__device__ __forceinline__ float sigmoidf(float x) { return 1.0f / (1.0f + __expf(-x)); }

__device__ __forceinline__ int lowerb(const int* __restrict__ a, int n, int v) {
    int lo = 0, hi = n;
    while (lo < hi) { int mid = (lo + hi) >> 1; if (a[mid] < v) lo = mid + 1; else hi = mid; }
    return lo;
}

// ---------------- runtime detection of primary_mask storage (u8 bool vs i32) --------
__global__ void mask_detect(const unsigned char* __restrict__ m, int n, int* __restrict__ flag) {
    __shared__ int f;
    if (threadIdx.x == 0) f = 0;
    __syncthreads();
    int local = 0;
    for (int i = threadIdx.x; i < n; i += blockDim.x)
        if ((i & 3) && m[i]) local = 1;
    if (local) atomicOr(&f, 1);
    __syncthreads();
    if (threadIdx.x == 0) *flag = f;
}

// ---------------- CSR build: histogram -> exclusive scan -> permute edges ------------
__global__ __launch_bounds__(256)
void edge_hist(const int* __restrict__ dst, int* __restrict__ cnt) {
    int e = blockIdx.x * 256 + threadIdx.x;
    if (e < NEDGE) atomicAdd(&cnt[dst[e]], 1);
}

__global__ __launch_bounds__(1024)
void scan_excl(const int* __restrict__ cnt, int* __restrict__ off, int n) {
    __shared__ int part[1024];
    int t = threadIdx.x;
    int chunk = (n + 1023) >> 10;
    int lo = t * chunk, hi = lo + chunk; if (hi > n) hi = n; if (lo > n) lo = n;
    int s = 0;
    for (int i = lo; i < hi; ++i) s += cnt[i];
    part[t] = s;
    __syncthreads();
    for (int o = 1; o < 1024; o <<= 1) {
        int v = (t >= o) ? part[t - o] : 0;
        __syncthreads();
        part[t] += v;
        __syncthreads();
    }
    int run = (t == 0) ? 0 : part[t - 1];
    for (int i = lo; i < hi; ++i) { off[i] = run; run += cnt[i]; }
    if (t == 1023) off[n] = part[1023];
}

// permute edges into dst-sorted order; precompute gate weight once per edge
__global__ __launch_bounds__(256)
void edge_scatter(const int* __restrict__ src, const int* __restrict__ dst,
                  const float* __restrict__ ea,
                  const float* __restrict__ wmix, const float* __restrict__ bmix,
                  int* __restrict__ cur, int* __restrict__ ssrc, float* __restrict__ swt) {
    int e = blockIdx.x * 256 + threadIdx.x;
    if (e >= NEDGE) return;
    int d = dst[e];
    int pos = atomicAdd(&cur[d], 1);
    ssrc[pos] = src[e];
    swt[pos] = sigmoidf(ea[e] * wmix[0] + bmix[0]);
}

// ---------------- gather: company side (2000 rows, deg~400) -------------------------
__global__ __launch_bounds__(256)
void gather_comp(const int* __restrict__ off, const int* __restrict__ ssrc,
                 const float* __restrict__ swt, const float* __restrict__ feat,
                 float* __restrict__ out) {
    __shared__ float tmp[128];
    int d = blockIdx.x;
    int lo = off[d], hi = off[d + 1];
    int h = threadIdx.x & 127;
    int slot = threadIdx.x >> 7;          // 2 edge slots for ILP
    float acc0 = 0.f, acc1 = 0.f;
    int j = lo + slot;
    for (; j + 2 < hi; j += 4) {
        int s0 = ssrc[j], s1 = ssrc[j + 2];
        float w0 = swt[j], w1 = swt[j + 2];
        acc0 += w0 * feat[(size_t)s0 * H + h];
        acc1 += w1 * feat[(size_t)s1 * H + h];
    }
    for (; j < hi; j += 2) acc0 += swt[j] * feat[(size_t)ssrc[j] * H + h];
    float acc = acc0 + acc1;
    if (slot == 1) tmp[h] = acc;
    __syncthreads();
    if (slot == 0) out[(size_t)d * H + h] = acc + tmp[h];
}

// ---------------- gather: fact side (100000 rows, deg~8, src table L2-resident) ------
__global__ __launch_bounds__(256)
void gather_fact(const int* __restrict__ off, const int* __restrict__ ssrc,
                 const float* __restrict__ swt, const float* __restrict__ feat,
                 float* __restrict__ out) {
    int d = blockIdx.x * 2 + (threadIdx.x >> 7);
    if (d >= NFACT) return;
    int h = threadIdx.x & 127;
    int lo = off[d], hi = off[d + 1];
    float acc = 0.f;
    for (int j = lo; j < hi; ++j)
        acc += swt[j] * feat[(size_t)ssrc[j] * H + h];
    out[(size_t)d * H + h] = acc;
}

// ---------------- fact encoder GEMM: out[m][h] = sum_k X[m][k]*W[h][k] + bias[h] -----
__global__ __launch_bounds__(256)
void gemm_bias_xwT(const float* __restrict__ X, const float* __restrict__ W,
                   const float* __restrict__ bias, float* __restrict__ out,
                   int M, int K) {
    __shared__ __align__(16) float As[16][68];
    __shared__ __align__(16) float Bs[16][132];
    const int tid = threadIdx.x;
    const int m0 = blockIdx.x * 64;
    const int tx = tid & 31;
    const int ty = tid >> 5;
    float acc[8][4];
#pragma unroll
    for (int i = 0; i < 8; ++i)
#pragma unroll
        for (int j = 0; j < 4; ++j) acc[i][j] = 0.f;

    const int lr = tid >> 2;
    const int lkq = tid & 3;
    int arow = m0 + lr; if (arow > M - 1) arow = M - 1;
    const float* xrow = X + (size_t)arow * K;
    const int ln = tid >> 1;
    const int lh = tid & 1;
    const float* wrow = W + (size_t)ln * K;

    for (int k0 = 0; k0 < K; k0 += 16) {
        float4 av  = *(const float4*)(xrow + k0 + lkq * 4);
        float4 bv0 = *(const float4*)(wrow + k0 + lh * 8);
        float4 bv1 = *(const float4*)(wrow + k0 + lh * 8 + 4);
        __syncthreads();
        As[lkq * 4 + 0][lr] = av.x; As[lkq * 4 + 1][lr] = av.y;
        As[lkq * 4 + 2][lr] = av.z; As[lkq * 4 + 3][lr] = av.w;
        {
            int kb = lh * 8;
            Bs[kb + 0][ln] = bv0.x; Bs[kb + 1][ln] = bv0.y;
            Bs[kb + 2][ln] = bv0.z; Bs[kb + 3][ln] = bv0.w;
            Bs[kb + 4][ln] = bv1.x; Bs[kb + 5][ln] = bv1.y;
            Bs[kb + 6][ln] = bv1.z; Bs[kb + 7][ln] = bv1.w;
        }
        __syncthreads();
#pragma unroll
        for (int k = 0; k < 16; ++k) {
            float4 a0 = *(const float4*)&As[k][ty * 8];
            float4 a1 = *(const float4*)&As[k][ty * 8 + 4];
            float4 b  = *(const float4*)&Bs[k][tx * 4];
            float a[8] = {a0.x, a0.y, a0.z, a0.w, a1.x, a1.y, a1.z, a1.w};
            float bb[4] = {b.x, b.y, b.z, b.w};
#pragma unroll
            for (int i = 0; i < 8; ++i)
#pragma unroll
                for (int j = 0; j < 4; ++j) acc[i][j] += a[i] * bb[j];
        }
    }
    float4 bsv = *(const float4*)(bias + tx * 4);
#pragma unroll
    for (int i = 0; i < 8; ++i) {
        int r = m0 + ty * 8 + i;
        if (r < M) {
            float4 o;
            o.x = acc[i][0] + bsv.x; o.y = acc[i][1] + bsv.y;
            o.z = acc[i][2] + bsv.z; o.w = acc[i][3] + bsv.w;
            *(float4*)(out + (size_t)r * H + tx * 4) = o;
        }
    }
}

// ---------------- fact combine: msg = msg@Wrel^T + brel + root@Wroot^T (in-place) ----
__global__ __launch_bounds__(256)
void gemm_combine_f(float* __restrict__ msg, const float* __restrict__ root,
                    const float* __restrict__ Wrel, const float* __restrict__ Wroot,
                    const float* __restrict__ brel, int M) {
    __shared__ __align__(16) float As[16][68];
    __shared__ __align__(16) float Bs[16][132];
    const int tid = threadIdx.x;
    const int m0 = blockIdx.x * 64;
    const int tx = tid & 31;
    const int ty = tid >> 5;
    float acc[8][4];
#pragma unroll
    for (int i = 0; i < 8; ++i)
#pragma unroll
        for (int j = 0; j < 4; ++j) acc[i][j] = 0.f;

    const int lr = tid >> 2;
    const int lkq = tid & 3;
    int arow = m0 + lr; if (arow > M - 1) arow = M - 1;
    const int ln = tid >> 1;
    const int lh = tid & 1;

    for (int k0 = 0; k0 < 256; k0 += 16) {
        int ka = k0 + lkq * 4;
        const float* asrc = (ka < 128) ? (msg + (size_t)arow * H + ka)
                                       : (root + (size_t)arow * H + (ka - 128));
        float4 av = *(const float4*)asrc;
        int kb = k0 + lh * 8;
        const float* bsrc = (kb < 128) ? (Wrel + (size_t)ln * H + kb)
                                       : (Wroot + (size_t)ln * H + (kb - 128));
        float4 bv0 = *(const float4*)bsrc;
        float4 bv1 = *(const float4*)(bsrc + 4);
        __syncthreads();
        As[lkq * 4 + 0][lr] = av.x; As[lkq * 4 + 1][lr] = av.y;
        As[lkq * 4 + 2][lr] = av.z; As[lkq * 4 + 3][lr] = av.w;
        {
            int kk = lh * 8;
            Bs[kk + 0][ln] = bv0.x; Bs[kk + 1][ln] = bv0.y;
            Bs[kk + 2][ln] = bv0.z; Bs[kk + 3][ln] = bv0.w;
            Bs[kk + 4][ln] = bv1.x; Bs[kk + 5][ln] = bv1.y;
            Bs[kk + 6][ln] = bv1.z; Bs[kk + 7][ln] = bv1.w;
        }
        __syncthreads();
#pragma unroll
        for (int k = 0; k < 16; ++k) {
            float4 a0 = *(const float4*)&As[k][ty * 8];
            float4 a1 = *(const float4*)&As[k][ty * 8 + 4];
            float4 b  = *(const float4*)&Bs[k][tx * 4];
            float a[8] = {a0.x, a0.y, a0.z, a0.w, a1.x, a1.y, a1.z, a1.w};
            float bb[4] = {b.x, b.y, b.z, b.w};
#pragma unroll
            for (int i = 0; i < 8; ++i)
#pragma unroll
                for (int j = 0; j < 4; ++j) acc[i][j] += a[i] * bb[j];
        }
    }
    float4 bsv = *(const float4*)(brel + tx * 4);
#pragma unroll
    for (int i = 0; i < 8; ++i) {
        int r = m0 + ty * 8 + i;
        if (r < M) {
            float4 o;
            o.x = acc[i][0] + bsv.x; o.y = acc[i][1] + bsv.y;
            o.z = acc[i][2] + bsv.z; o.w = acc[i][3] + bsv.w;
            *(float4*)(msg + (size_t)r * H + tx * 4) = o;
        }
    }
}

// ---------------- company encoder (tiny K=27) ----------------------------------------
__global__ __launch_bounds__(128)
void enc_comp(const float* __restrict__ X, const float* __restrict__ W,
              const float* __restrict__ bias, float* __restrict__ out) {
    __shared__ float xr[DC];
    int n = blockIdx.x, h = threadIdx.x;
    if (h < DC) xr[h] = X[(size_t)n * DC + h];
    __syncthreads();
    float acc = bias[h];
    const float* w = W + (size_t)h * DC;
#pragma unroll
    for (int d = 0; d < DC; ++d) acc += xr[d] * w[d];
    out[(size_t)n * H + h] = acc;
}

// ---------------- company combine -----------------------------------------------------
__global__ __launch_bounds__(128)
void combine_c(const float* __restrict__ msgc, const float* __restrict__ hc,
               const float* __restrict__ Wrel, const float* __restrict__ Wroot,
               const float* __restrict__ brel, float* __restrict__ out) {
    __shared__ float rowA[H];
    __shared__ float rowB[H];
    int n = blockIdx.x, h = threadIdx.x;
    rowA[h] = msgc[(size_t)n * H + h];
    rowB[h] = hc[(size_t)n * H + h];
    __syncthreads();
    float acc = brel[h];
    const float* wr = Wrel + (size_t)h * H;
    const float* wo = Wroot + (size_t)h * H;
#pragma unroll 4
    for (int k = 0; k < H; ++k) acc += rowA[k] * wr[k] + rowB[k] * wo[k];
    out[(size_t)n * H + h] = acc;
}

// ---------------- relu + LayerNorm over H, in place (wave per row) -------------------
__global__ __launch_bounds__(256)
void relu_ln_rows(float* __restrict__ data, int M,
                  const float* __restrict__ g, const float* __restrict__ b) {
    int row = blockIdx.x * 4 + (threadIdx.x >> 6);
    int lane = threadIdx.x & 63;
    if (row >= M) return;
    float* p = data + (size_t)row * H;
    float2 v = *(float2*)(p + lane * 2);
    float x0 = fmaxf(v.x, 0.f), x1 = fmaxf(v.y, 0.f);
    float s = x0 + x1, q = x0 * x0 + x1 * x1;
#pragma unroll
    for (int o = 32; o > 0; o >>= 1) { s += __shfl_xor(s, o); q += __shfl_xor(q, o); }
    float mu = s * (1.f / H);
    float var = q * (1.f / H) - mu * mu;
    float rs = rsqrtf(var + LEPS);
    float2 gg = *(const float2*)(g + lane * 2);
    float2 bb = *(const float2*)(b + lane * 2);
    float2 o2;
    o2.x = (x0 - mu) * rs * gg.x + bb.x;
    o2.y = (x1 - mu) * rs * gg.y + bb.y;
    *(float2*)(p + lane * 2) = o2;
}

// ---------------- pooling ------------------------------------------------------------
__global__ __launch_bounds__(128)
void pool_fact(const float* __restrict__ hf, const int* __restrict__ batch,
               float* __restrict__ pool) {
    int b = blockIdx.x, h = threadIdx.x;
    int lo = lowerb(batch, NFACT, b), hi = lowerb(batch, NFACT, b + 1);
    float acc = 0.f;
    for (int r = lo; r < hi; ++r) acc += hf[(size_t)r * H + h];
    float cnt = (float)(hi - lo); if (cnt < 1.f) cnt = 1.f;
    pool[(size_t)b * H + h] = acc / cnt;
}

// NOTE: reference applies maximum(cnt_m,1) BEFORE the where test -> fallback is dead.
__global__ __launch_bounds__(128)
void pool_comp(const float* __restrict__ hc, const int* __restrict__ batch,
               const void* __restrict__ maskp, const int* __restrict__ flag,
               float* __restrict__ pool) {
    int b = blockIdx.x, h = threadIdx.x;
    int lo = lowerb(batch, NCOMP, b), hi = lowerb(batch, NCOMP, b + 1);
    int isU8 = *flag;
    const unsigned char* m8 = (const unsigned char*)maskp;
    const int* m32 = (const int*)maskp;
    float acc = 0.f, cnt = 0.f;
    for (int r = lo; r < hi; ++r) {
        float m = isU8 ? (m8[r] ? 1.f : 0.f) : (m32[r] ? 1.f : 0.f);
        acc += m * hc[(size_t)r * H + h];
        cnt += m;
    }
    if (cnt < 1.f) cnt = 1.f;
    pool[(size_t)b * H + h] = acc / cnt;
}

// ---------------- gated readout + classifier -----------------------------------------
__global__ __launch_bounds__(128)
void gate_cls(const float* __restrict__ fp, const float* __restrict__ cp,
              const float* __restrict__ Wg, const float* __restrict__ bg,
              const float* __restrict__ Wc, const float* __restrict__ bc,
              float* __restrict__ out) {
    __shared__ float red[2];
    __shared__ float red2[2];
    int b = blockIdx.x, t = threadIdx.x;
    float f = fp[(size_t)b * H + t], c = cp[(size_t)b * H + t];
    float s = Wg[t] * f + Wg[H + t] * c;
#pragma unroll
    for (int o = 32; o > 0; o >>= 1) s += __shfl_xor(s, o);
    if ((t & 63) == 0) red[t >> 6] = s;
    __syncthreads();
    float S = red[0] + red[1];
    float alpha = sigmoidf(S + bg[0]);
    float v = (alpha * f + (1.f - alpha) * c) * Wc[t];
#pragma unroll
    for (int o = 32; o > 0; o >>= 1) v += __shfl_xor(v, o);
    if ((t & 63) == 0) red2[t >> 6] = v;
    __syncthreads();
    if (t == 0) out[b] = red2[0] + red2[1] + bc[0];
}

extern "C" void kernel_launch(void* const* d_in, const int* in_sizes, int n_in,
                              void* d_out, int out_size, void* d_ws, size_t ws_size,
                              hipStream_t stream) {
    const float* x_fact   = (const float*)d_in[0];
    const float* x_comp   = (const float*)d_in[1];
    const float* ea_fc    = (const float*)d_in[2];
    const float* ea_cf    = (const float*)d_in[3];
    const int*   src_fc   = (const int*)d_in[4];
    const int*   dst_fc   = (const int*)d_in[5];
    const int*   src_cf   = (const int*)d_in[6];
    const int*   dst_cf   = (const int*)d_in[7];
    const int*   fact_batch = (const int*)d_in[8];
    const int*   comp_batch = (const int*)d_in[9];
    const void*  pmask    = d_in[10];
    const float* W_in_f   = (const float*)d_in[11];
    const float* b_in_f   = (const float*)d_in[12];
    const float* g_in_f   = (const float*)d_in[13];
    const float* be_in_f  = (const float*)d_in[14];
    const float* W_in_c   = (const float*)d_in[15];
    const float* b_in_c   = (const float*)d_in[16];
    const float* g_in_c   = (const float*)d_in[17];
    const float* be_in_c  = (const float*)d_in[18];
    const float* w_mix    = (const float*)d_in[19];
    const float* b_mix    = (const float*)d_in[20];
    const float* Wrel_fc  = (const float*)d_in[21];
    const float* brel_fc  = (const float*)d_in[22];
    const float* Wroot_fc = (const float*)d_in[23];
    const float* Wrel_cf  = (const float*)d_in[24];
    const float* brel_cf  = (const float*)d_in[25];
    const float* Wroot_cf = (const float*)d_in[26];
    const float* g_post_f = (const float*)d_in[27];
    const float* b_post_f = (const float*)d_in[28];
    const float* g_post_c = (const float*)d_in[29];
    const float* b_post_c = (const float*)d_in[30];
    const float* W_gate   = (const float*)d_in[31];
    const float* b_gate   = (const float*)d_in[32];
    const float* W_cls    = (const float*)d_in[33];
    const float* b_cls    = (const float*)d_in[34];
    float* outp = (float*)d_out;
    (void)in_sizes; (void)n_in; (void)out_size; (void)ws_size;

    float* buf0  = (float*)d_ws;                        // hf ping  [NFACT,H]
    float* buf1  = buf0 + (size_t)NFACT * H;            // hf pong
    float* hc0   = buf1 + (size_t)NFACT * H;            // hc ping  [NCOMP,H]
    float* hc1   = hc0 + (size_t)NCOMP * H;             // hc pong
    float* msgc  = hc1 + (size_t)NCOMP * H;             // msg_c    [NCOMP,H]
    float* fpool = msgc + (size_t)NCOMP * H;            // [B,H]
    float* cpool = fpool + (size_t)BGRAPH * H;          // [B,H]
    float* swt_fc = cpool + (size_t)BGRAPH * H;         // [E]
    float* swt_cf = swt_fc + (size_t)NEDGE;             // [E]
    int*   ssrc_fc = (int*)(swt_cf + (size_t)NEDGE);    // [E]
    int*   ssrc_cf = ssrc_fc + (size_t)NEDGE;           // [E]
    int*   off_fc  = ssrc_cf + (size_t)NEDGE;           // [NCOMP+1]
    int*   cur_fc  = off_fc + (NCOMP + 1);              // [NCOMP]
    int*   off_cf  = cur_fc + NCOMP;                    // [NFACT+1]
    int*   cur_cf  = off_cf + (NFACT + 1);              // [NFACT]
    int*   flag    = cur_cf + NFACT;

    mask_detect<<<1, 256, 0, stream>>>((const unsigned char*)pmask, NCOMP, flag);

    // ---- CSR build (once; weights reused across both layers) ----
    hipMemsetAsync(cur_fc, 0, NCOMP * sizeof(int), stream);
    hipMemsetAsync(cur_cf, 0, NFACT * sizeof(int), stream);
    edge_hist<<<(NEDGE + 255) / 256, 256, 0, stream>>>(dst_fc, cur_fc);
    edge_hist<<<(NEDGE + 255) / 256, 256, 0, stream>>>(dst_cf, cur_cf);
    scan_excl<<<1, 1024, 0, stream>>>(cur_fc, off_fc, NCOMP);
    scan_excl<<<1, 1024, 0, stream>>>(cur_cf, off_cf, NFACT);
    hipMemcpyAsync(cur_fc, off_fc, NCOMP * sizeof(int), hipMemcpyDeviceToDevice, stream);
    hipMemcpyAsync(cur_cf, off_cf, NFACT * sizeof(int), hipMemcpyDeviceToDevice, stream);
    edge_scatter<<<(NEDGE + 255) / 256, 256, 0, stream>>>(src_fc, dst_fc, ea_fc, w_mix, b_mix,
                                                          cur_fc, ssrc_fc, swt_fc);
    edge_scatter<<<(NEDGE + 255) / 256, 256, 0, stream>>>(src_cf, dst_cf, ea_cf, w_mix, b_mix,
                                                          cur_cf, ssrc_cf, swt_cf);

    // ---- encoders ----
    gemm_bias_xwT<<<(NFACT + 63) / 64, 256, 0, stream>>>(x_fact, W_in_f, b_in_f, buf0, NFACT, DF);
    relu_ln_rows<<<(NFACT + 3) / 4, 256, 0, stream>>>(buf0, NFACT, g_in_f, be_in_f);
    enc_comp<<<NCOMP, 128, 0, stream>>>(x_comp, W_in_c, b_in_c, hc0);
    relu_ln_rows<<<(NCOMP + 3) / 4, 256, 0, stream>>>(hc0, NCOMP, g_in_c, be_in_c);

    float* hf = buf0; float* hfN = buf1;
    float* hc = hc0;  float* hcN = hc1;

    for (int l = 0; l < 2; ++l) {
        gather_comp<<<NCOMP, 256, 0, stream>>>(off_fc, ssrc_fc, swt_fc, hf, msgc);
        gather_fact<<<(NFACT + 1) / 2, 256, 0, stream>>>(off_cf, ssrc_cf, swt_cf, hc, hfN);
        gemm_combine_f<<<(NFACT + 63) / 64, 256, 0, stream>>>(hfN, hf,
            Wrel_cf + (size_t)l * H * H, Wroot_cf + (size_t)l * H * H, brel_cf + (size_t)l * H, NFACT);
        relu_ln_rows<<<(NFACT + 3) / 4, 256, 0, stream>>>(hfN, NFACT, g_post_f, b_post_f);
        combine_c<<<NCOMP, 128, 0, stream>>>(msgc, hc,
            Wrel_fc + (size_t)l * H * H, Wroot_fc + (size_t)l * H * H, brel_fc + (size_t)l * H, hcN);
        relu_ln_rows<<<(NCOMP + 3) / 4, 256, 0, stream>>>(hcN, NCOMP, g_post_c, b_post_c);
        float* t = hf; hf = hfN; hfN = t;
        t = hc; hc = hcN; hcN = t;
    }

    pool_fact<<<BGRAPH, 128, 0, stream>>>(hf, fact_batch, fpool);
    pool_comp<<<BGRAPH, 128, 0, stream>>>(hc, comp_batch, pmask, flag, cpool);
    gate_cls<<<BGRAPH, 128, 0, stream>>>(fpool, cpool, W_gate, b_gate, W_cls, b_cls, outp);
}